// Round 1
// baseline (2237.109 us; speedup 1.0000x reference)
//
#include <hip/hip_runtime.h>
#include <math.h>

#define NPROTO 8
#define KV_NCH 4
#define MSG_NCH 8

typedef __attribute__((ext_vector_type(8))) short short8;
typedef __attribute__((ext_vector_type(4))) float floatx4;

static __device__ __forceinline__ ushort f2b(float f) {
    unsigned u = __builtin_bit_cast(unsigned, f);
    unsigned r = (u + 0x7fffu + ((u >> 16) & 1u)) >> 16;
    return (ushort)r;
}

static __device__ __forceinline__ float elu1(float v) {
    return v > 0.f ? v + 1.f : __expf(v);
}

// ---------------- prototype projection / argmax-class kernel ----------------
// thread-per-token, LDS channel tiles (XOR-swizzled, ds_read_b128 conflict-free)
__global__ __launch_bounds__(256) void lft_class_kernel(
    const float* __restrict__ f0wo, const float* __restrict__ f1wo,
    const int* __restrict__ mask0, const int* __restrict__ mask1,
    const float* __restrict__ proto,
    float* out, int* cls0, int* cls1)
{
    __shared__ float pr[2048];          // proto [8][256]
    __shared__ float tile[256][64];     // [token][ch], swizzled in ch
    int t = threadIdx.x;
    *(float4*)&pr[t * 4]        = *(const float4*)&proto[t * 4];
    *(float4*)&pr[1024 + t * 4] = *(const float4*)&proto[1024 + t * 4];
    long tok0 = (long)blockIdx.x * 256;
    const float* fsrc; const int* msrc; float* fpout; float* clsout; int* clsarr; long tbase;
    if (tok0 < 38400) {
        tbase = tok0; fsrc = f0wo; msrc = mask0;
        fpout = out + 19737600L; clsout = out + 19660800L; clsarr = cls0;
    } else {
        tbase = tok0 - 38400; fsrc = f1wo; msrc = mask1;
        fpout = out + 20044800L; clsout = out + 19699200L; clsarr = cls1;
    }
    float s[NPROTO] = {};
    int r0 = t >> 4;            // 0..15
    int c4 = (t & 15) << 2;     // 0..60
    for (int ct = 0; ct < 4; ct++) {
        __syncthreads();
#pragma unroll
        for (int rr = 0; rr < 16; rr++) {
            int row = rr * 16 + r0;
            float4 v = *(const float4*)&fsrc[(tbase + row) * 256 + ct * 64 + c4];
            *(float4*)&tile[row][c4 ^ ((row & 7) << 2)] = v;
        }
        __syncthreads();
#pragma unroll
        for (int cc = 0; cc < 16; cc++) {
            float4 f = *(const float4*)&tile[t][(cc << 2) ^ ((t & 7) << 2)];
#pragma unroll
            for (int p = 0; p < NPROTO; p++) {
                float4 pv = *(const float4*)&pr[p * 256 + ct * 64 + (cc << 2)];
                s[p] += f.x * pv.x + f.y * pv.y + f.z * pv.z + f.w * pv.w;
            }
        }
    }
    long tok = tbase + t;
    int best = 0; float bv = s[0];
#pragma unroll
    for (int p = 1; p < NPROTO; p++) { if (s[p] > bv) { bv = s[p]; best = p; } }
#pragma unroll
    for (int p = 0; p < NPROTO; p++) fpout[tok * 8 + p] = s[p];
    clsout[tok] = (float)best;
    clsarr[tok] = msrc[tok] ? best : -1;
}

// ---------------- counting sort of tokens by (batch,class) -------------------
__global__ __launch_bounds__(256) void lft_sort_kernel(
    const int* __restrict__ cls0, const int* __restrict__ cls1,
    int* tl0, int* tl1, int* meta)
{
    int g = blockIdx.x; int L = g >> 3, b = g & 7;
    const int* cls = (L ? cls1 : cls0) + b * 4800;
    int* tl = (L ? tl1 : tl0) + b * 4800;
    int* mt = meta + (L * 8 + b) * 16;
    __shared__ int cnt[8], base[8], pos[8];
    int t = threadIdx.x;
    if (t < 8) cnt[t] = 0;
    __syncthreads();
    for (int tok = t; tok < 4800; tok += 256) {
        int c = cls[tok];
        if (c >= 0) atomicAdd(&cnt[c], 1);
    }
    __syncthreads();
    if (t == 0) {
        int s = 0;
        for (int c = 0; c < 8; c++) { base[c] = s; pos[c] = s; s += cnt[c]; }
    }
    __syncthreads();
    if (t < 8) { mt[t * 2] = base[t]; mt[t * 2 + 1] = cnt[t]; }
    for (int tok = t; tok < 4800; tok += 256) {
        int c = cls[tok];
        if (c >= 0) { int p = atomicAdd(&pos[c], 1); tl[p] = tok; }
    }
}

// ---------------- weight convert + transpose: Wt[n*K+k] = bf16(W[k*N+n]) ----
__global__ __launch_bounds__(256) void lft_wconv_kernel(
    const float* W0, const float* W1p, const float* W2p, const float* W3p,
    int K, int N, int nTypes, ushort* dst)
{
    int z = blockIdx.z;
    int li = z / nTypes, mi = z % nTypes;
    const float* srcs[4] = {W0, W1p, W2p, W3p};
    const float* src = srcs[mi] + (size_t)li * K * N;
    ushort* outp = dst + (size_t)z * K * N;
    __shared__ float tile[32][33];
    int k0 = blockIdx.x * 32, n0 = blockIdx.y * 32;
    int t = threadIdx.x;
    int r = t >> 3, c4 = (t & 7) << 2;
    float4 v = *(const float4*)&src[(size_t)(k0 + r) * N + n0 + c4];
    tile[r][c4] = v.x; tile[r][c4 + 1] = v.y; tile[r][c4 + 2] = v.z; tile[r][c4 + 3] = v.w;
    __syncthreads();
    ushort4 o;
    o.x = f2b(tile[c4 + 0][r]);
    o.y = f2b(tile[c4 + 1][r]);
    o.z = f2b(tile[c4 + 2][r]);
    o.w = f2b(tile[c4 + 3][r]);
    *(ushort4*)&outp[(size_t)(n0 + r) * K + k0 + c4] = o;
}

// ---------------- bf16 cast of feat0/feat1 (shadows only) ----------------
__global__ __launch_bounds__(256) void lft_cast_kernel(
    const float* __restrict__ f0, const float* __restrict__ f1,
    ushort* fab, ushort* fbb)
{
    long idx = ((long)blockIdx.x * 256 + threadIdx.x) * 4;
    const float* src; ushort* db; long o;
    if (idx < 9830400L) { src = f0; db = fab; o = idx; }
    else                { src = f1; db = fbb; o = idx - 9830400L; }
    float4 v = *(const float4*)&src[o];
    ushort4 u; u.x = f2b(v.x); u.y = f2b(v.y); u.z = f2b(v.z); u.w = f2b(v.w);
    *(ushort4*)&db[o] = u;
}

// ---------------- bf16 MFMA GEMM: C[38400,N] = act([A0|A1] @ Wt^T) ----------
// act: 0 none, 1 elu+1, 2 relu  -> Cf (fp32, stride N) / Cb (bf16, stride N)
// act 3: qkv-fused N=768: col<256 -> Cb=q bf16 elu ; <512 -> Cf=phi_k fp32 ;
//        else Cv=v fp32.   act 4: kv-fused N=512: Cf=phi_k ; Cv=v.
__global__ __launch_bounds__(256) void lft_mfma_gemm(
    const ushort* __restrict__ A0, const ushort* __restrict__ A1, int kSplit,
    const ushort* __restrict__ Wt,
    float* Cf, ushort* Cb, float* Cv, int N, int K, int act)
{
    __shared__ ushort As[128 * 40];
    __shared__ ushort Bs[128 * 40];
    int t = threadIdx.x;
    int m0 = blockIdx.y << 7;
    int n0 = blockIdx.x << 7;
    int wave = t >> 6, lane = t & 63;
    int wm = wave >> 1, wn = wave & 1;
    int l16 = lane & 15, quad = lane >> 4;
    floatx4 acc[4][4] = {};
    int rowA = t >> 2;            // 0..63
    int coff = (t & 3) << 3;      // 0,8,16,24
    for (int k0 = 0; k0 < K; k0 += 32) {
        const ushort* Asrc; int kcol, ldA;
        if (k0 < kSplit) { Asrc = A0; kcol = k0;          ldA = kSplit; }
        else             { Asrc = A1; kcol = k0 - kSplit; ldA = K - kSplit; }
        uint4 a0 = *(const uint4*)&Asrc[(size_t)(m0 + rowA) * ldA + kcol + coff];
        uint4 a1 = *(const uint4*)&Asrc[(size_t)(m0 + rowA + 64) * ldA + kcol + coff];
        uint4 b0 = *(const uint4*)&Wt[(size_t)(n0 + rowA) * K + k0 + coff];
        uint4 b1 = *(const uint4*)&Wt[(size_t)(n0 + rowA + 64) * K + k0 + coff];
        __syncthreads();
        *(uint4*)&As[rowA * 40 + coff] = a0;
        *(uint4*)&As[(rowA + 64) * 40 + coff] = a1;
        *(uint4*)&Bs[rowA * 40 + coff] = b0;
        *(uint4*)&Bs[(rowA + 64) * 40 + coff] = b1;
        __syncthreads();
        short8 af[4], bfr[4];
#pragma unroll
        for (int i = 0; i < 4; i++) {
            af[i]  = *(const short8*)&As[(wm * 64 + i * 16 + l16) * 40 + quad * 8];
            bfr[i] = *(const short8*)&Bs[(wn * 64 + i * 16 + l16) * 40 + quad * 8];
        }
#pragma unroll
        for (int i = 0; i < 4; i++)
#pragma unroll
            for (int j = 0; j < 4; j++)
                acc[i][j] = __builtin_amdgcn_mfma_f32_16x16x32_bf16(af[i], bfr[j], acc[i][j], 0, 0, 0);
    }
#pragma unroll
    for (int i = 0; i < 4; i++) {
#pragma unroll
        for (int j = 0; j < 4; j++) {
#pragma unroll
            for (int r = 0; r < 4; r++) {
                float v = acc[i][j][r];
                long row = m0 + wm * 64 + i * 16 + quad * 4 + r;
                int col = n0 + wn * 64 + j * 16 + l16;
                if (act == 3) {
                    if (col < 256)      Cb[row * 256 + col] = f2b(elu1(v));
                    else if (col < 512) Cf[row * 256 + col - 256] = elu1(v);
                    else                Cv[row * 256 + col - 512] = v;
                } else if (act == 4) {
                    if (col < 256) Cf[row * 256 + col] = elu1(v);
                    else           Cv[row * 256 + col - 256] = v;
                } else {
                    if (act == 1)      v = elu1(v);
                    else if (act == 2) v = fmaxf(v, 0.f);
                    if (Cf) Cf[row * N + col] = v;
                    if (Cb) Cb[row * N + col] = f2b(v);
                }
            }
        }
    }
}

// ---------------- fused GEMM (N=256) + row-LayerNorm epilogue ----------------
// C = [A0|A1](38400xK) @ Wt(256xK)^T, then per-row LN over 256 cols,
// optional residual+mask, outputs fp32 (outF) and/or bf16 (outB).
// Tile: M=64 rows/block (grid 600), all 256 cols; wave w owns cols [64w,64w+64).
__global__ __launch_bounds__(256) void lft_gemm_ln(
    const ushort* __restrict__ A0, const ushort* __restrict__ A1, int kSplit,
    const ushort* __restrict__ Wt, int K,
    const float* __restrict__ g, const float* __restrict__ bb,
    const float* __restrict__ resid, const int* __restrict__ cls,
    float* outF, ushort* __restrict__ outB)
{
    __shared__ ushort As[64 * 40];
    __shared__ ushort Bs[256 * 40];
    __shared__ float gs[256], bs[256];
    __shared__ float psum[4][64], psq[4][64];
    int t = threadIdx.x;
    long m0 = (long)blockIdx.x << 6;
    int wave = t >> 6, lane = t & 63;
    int l16 = lane & 15, quad = lane >> 4;
    gs[t] = g[t]; bs[t] = bb[t];
    floatx4 acc[4][4] = {};
    int rowA = t >> 2;            // 0..63
    int coff = (t & 3) << 3;      // 0,8,16,24
    for (int k0 = 0; k0 < K; k0 += 32) {
        const ushort* Asrc; int kcol, ldA;
        if (k0 < kSplit) { Asrc = A0; kcol = k0;          ldA = kSplit; }
        else             { Asrc = A1; kcol = k0 - kSplit; ldA = K - kSplit; }
        uint4 a0 = *(const uint4*)&Asrc[(m0 + rowA) * ldA + kcol + coff];
        uint4 b0 = *(const uint4*)&Wt[(size_t)(rowA)       * K + k0 + coff];
        uint4 b1 = *(const uint4*)&Wt[(size_t)(rowA + 64)  * K + k0 + coff];
        uint4 b2 = *(const uint4*)&Wt[(size_t)(rowA + 128) * K + k0 + coff];
        uint4 b3 = *(const uint4*)&Wt[(size_t)(rowA + 192) * K + k0 + coff];
        __syncthreads();
        *(uint4*)&As[rowA * 40 + coff] = a0;
        *(uint4*)&Bs[rowA * 40 + coff] = b0;
        *(uint4*)&Bs[(rowA + 64) * 40 + coff] = b1;
        *(uint4*)&Bs[(rowA + 128) * 40 + coff] = b2;
        *(uint4*)&Bs[(rowA + 192) * 40 + coff] = b3;
        __syncthreads();
        short8 af[4], bfr[4];
#pragma unroll
        for (int i = 0; i < 4; i++) {
            af[i]  = *(const short8*)&As[(i * 16 + l16) * 40 + quad * 8];
            bfr[i] = *(const short8*)&Bs[(wave * 64 + i * 16 + l16) * 40 + quad * 8];
        }
#pragma unroll
        for (int i = 0; i < 4; i++)
#pragma unroll
            for (int j = 0; j < 4; j++)
                acc[i][j] = __builtin_amdgcn_mfma_f32_16x16x32_bf16(af[i], bfr[j], acc[i][j], 0, 0, 0);
    }
    // per-row partial sums (this wave's 64 cols) -> LDS
#pragma unroll
    for (int i = 0; i < 4; i++) {
#pragma unroll
        for (int r = 0; r < 4; r++) {
            float s = 0.f, q = 0.f;
#pragma unroll
            for (int j = 0; j < 4; j++) { float v = acc[i][j][r]; s += v; q += v * v; }
#pragma unroll
            for (int o = 8; o >= 1; o >>= 1) {
                s += __shfl_xor(s, o, 64);
                q += __shfl_xor(q, o, 64);
            }
            if (l16 == 0) {
                int row = i * 16 + quad * 4 + r;
                psum[wave][row] = s; psq[wave][row] = q;
            }
        }
    }
    __syncthreads();
    if (t < 64) {
        float s = psum[0][t] + psum[1][t] + psum[2][t] + psum[3][t];
        float q = psq[0][t] + psq[1][t] + psq[2][t] + psq[3][t];
        float mean = s * (1.0f / 256.0f);
        float var = q * (1.0f / 256.0f) - mean * mean;
        psum[0][t] = mean;
        psq[0][t] = rsqrtf(var + 1e-5f);
    }
    __syncthreads();
#pragma unroll
    for (int i = 0; i < 4; i++) {
#pragma unroll
        for (int r = 0; r < 4; r++) {
            int rloc = i * 16 + quad * 4 + r;
            long grow = m0 + rloc;
            float mean = psum[0][rloc], rstd = psq[0][rloc];
            int cv = cls ? cls[grow] : 0;
#pragma unroll
            for (int j = 0; j < 4; j++) {
                int col = wave * 64 + j * 16 + l16;
                float y = (acc[i][j][r] - mean) * rstd * gs[col] + bs[col];
                if (resid) {
                    float xr = resid[grow * 256 + col];
                    y = (cv >= 0) ? xr + y : xr;
                }
                if (outF) outF[grow * 256 + col] = y;
                outB[grow * 256 + col] = f2b(y);
            }
        }
    }
}

// ---------------- per-class KV / Ksum reduction (SRC-side token lists) --------
__global__ __launch_bounds__(256) void lft_kv_kernel(
    const float* __restrict__ phik, const float* __restrict__ vmat,
    const int* __restrict__ tlist, const int* __restrict__ meta,
    float* kv, float* ksum)
{
    int chunk = blockIdx.x, c = blockIdx.y;
    int b = blockIdx.z >> 3, h = blockIdx.z & 7;
    int off = meta[(b * 8 + c) * 2], n = meta[(b * 8 + c) * 2 + 1];
    int per = (n + KV_NCH - 1) / KV_NCH;
    int s0 = chunk * per;
    int s1 = min(s0 + per, n);
    if (s0 >= s1) return;
    const int* tl = tlist + b * 4800 + off;
    int t = threadIdx.x;
    __shared__ float kb[8][32];
    __shared__ float vb[8][32];
    int od = t >> 3, oe = (t & 7) << 2;
    int lt = t >> 5, ld = t & 31;
    float a0 = 0.f, a1 = 0.f, a2 = 0.f, a3 = 0.f, ak = 0.f;
    for (int s = s0; s < s1; s += 8) {
        float kval = 0.f, vval = 0.f;
        if (s + lt < s1) {
            int tok = tl[s + lt];
            long bse = ((long)b * 4800 + tok) * 256 + h * 32 + ld;
            kval = phik[bse];
            vval = vmat[bse];
        }
        __syncthreads();
        kb[lt][ld] = kval;
        vb[lt][ld] = vval;
        __syncthreads();
#pragma unroll
        for (int j = 0; j < 8; j++) {
            float kd = kb[j][od];
            float4 vv = *(const float4*)&vb[j][oe];
            a0 += kd * vv.x; a1 += kd * vv.y; a2 += kd * vv.z; a3 += kd * vv.w;
            ak += kd;
        }
    }
    float* dst = kv + (((long)(b * NPROTO + c) * 8 + h) << 10) + od * 32 + oe;
    atomicAdd(dst + 0, a0);
    atomicAdd(dst + 1, a1);
    atomicAdd(dst + 2, a2);
    atomicAdd(dst + 3, a3);
    if ((t & 7) == 0)
        atomicAdd(ksum + (((long)(b * NPROTO + c) * 8 + h) << 5) + od, ak);
}

// ---------------- kv fp32 [d][e] + ksum → bf16 B-layout [e'][d], e'<48 -------
__global__ __launch_bounds__(256) void lft_kvconv_kernel(
    const float* __restrict__ kvb, const float* __restrict__ ksb,
    ushort* __restrict__ kvt)
{
    int bc = blockIdx.x;          // b*8+c
    int t = threadIdx.x;
    int h = t >> 5, d = t & 31;
    const float* kvsrc = kvb + ((long)bc * 8 + h) * 1024;
    const float* kssrc = ksb + ((long)bc * 8 + h) * 32;
    ushort* dst = kvt + ((long)bc * 8 + h) * 1536;
#pragma unroll
    for (int e = 0; e < 32; e++) dst[e * 32 + d] = f2b(kvsrc[d * 32 + e]);
    dst[32 * 32 + d] = f2b(kssrc[d]);
#pragma unroll
    for (int e = 33; e < 48; e++) dst[e * 32 + d] = 0;
}

// ---------------- msg via MFMA over X-SIDE class-sorted lists ----------------
__global__ __launch_bounds__(256) void lft_msg_kernel(
    const ushort* __restrict__ pq, const ushort* __restrict__ kvt,
    const int* __restrict__ tlist, const int* __restrict__ meta,
    ushort* __restrict__ msg)
{
    int chunk = blockIdx.x, c = blockIdx.y, b = blockIdx.z;
    int off = meta[(b * 8 + c) * 2], n = meta[(b * 8 + c) * 2 + 1];
    int per = (n + MSG_NCH - 1) / MSG_NCH;
    int s0 = chunk * per, s1 = min(s0 + per, n);
    if (s0 >= s1) return;
    const int* tl = tlist + b * 4800 + off;
    int t = threadIdx.x;
    int wave = t >> 6, lane = t & 63;
    int l16 = lane & 15, quad = lane >> 4;
    int bc = b * 8 + c;
    short8 bfr[2][3];
#pragma unroll
    for (int hh = 0; hh < 2; hh++) {
        int h = wave * 2 + hh;
        const ushort* kb = kvt + ((long)bc * 8 + h) * 1536;
#pragma unroll
        for (int nt = 0; nt < 3; nt++)
            bfr[hh][nt] = *(const short8*)&kb[(nt * 16 + l16) * 32 + quad * 8];
    }
    for (int s = s0; s < s1; s += 16) {
        int ia = min(s + l16, s1 - 1);
        int tokA = tl[ia];
        long rowA = (long)b * 4800 + tokA;
#pragma unroll
        for (int hh = 0; hh < 2; hh++) {
            int h = wave * 2 + hh;
            short8 a = *(const short8*)&pq[rowA * 256 + h * 32 + quad * 8];
            floatx4 n0 = {}, n1 = {}, dd = {};
            n0 = __builtin_amdgcn_mfma_f32_16x16x32_bf16(a, bfr[hh][0], n0, 0, 0, 0);
            n1 = __builtin_amdgcn_mfma_f32_16x16x32_bf16(a, bfr[hh][1], n1, 0, 0, 0);
            dd = __builtin_amdgcn_mfma_f32_16x16x32_bf16(a, bfr[hh][2], dd, 0, 0, 0);
#pragma unroll
            for (int r = 0; r < 4; r++) {
                int rowi = s + quad * 4 + r;
                float den = __shfl(dd[r], lane & 48, 64);
                float inv = 1.f / (den + 1e-6f);
                int tokr = __shfl(tokA, quad * 4 + r, 64);
                if (rowi < s1) {
                    long base = ((long)b * 4800 + tokr) * 256 + h * 32;
                    msg[base + l16]      = f2b(n0[r] * inv);
                    msg[base + 16 + l16] = f2b(n1[r] * inv);
                }
            }
        }
    }
}

extern "C" void kernel_launch(void* const* d_in, const int* in_sizes, int n_in,
                              void* d_out, int out_size, void* d_ws, size_t ws_size,
                              hipStream_t stream)
{
    (void)in_sizes; (void)n_in; (void)out_size; (void)ws_size;
    const float* feat0 = (const float*)d_in[0];
    const float* feat1 = (const float*)d_in[1];
    const int*   mask0 = (const int*)d_in[2];
    const int*   mask1 = (const int*)d_in[3];
    const float* f0wo  = (const float*)d_in[4];
    const float* f1wo  = (const float*)d_in[5];
    const float* proto = (const float*)d_in[6];
    const float* Wq = (const float*)d_in[7];
    const float* Wk = (const float*)d_in[8];
    const float* Wv = (const float*)d_in[9];
    const float* Wm = (const float*)d_in[10];
    const float* W1 = (const float*)d_in[11];
    const float* W2 = (const float*)d_in[12];
    const float* g1 = (const float*)d_in[13];
    const float* b1 = (const float*)d_in[14];
    const float* g2 = (const float*)d_in[15];
    const float* b2 = (const float*)d_in[16];
    float* out = (float*)d_out;
    float* ws = (float*)d_ws;

    // ---- workspace layout (unchanged) ----
    const long FSZ = 9830400L;           // 8*4800*256
    float* fa   = ws;
    float* fb   = ws + FSZ;
    float* kbuf = ws + 2 * FSZ;          // phi_k fp32
    float* vbuf = ws + 3 * FSZ;          // v fp32 ; later reused as hid_bf
    ushort* ub  = (ushort*)(ws + 4 * FSZ);
    ushort* fa_bf  = ub;
    ushort* fb_bf  = ub + FSZ;
    ushort* msg_bf = ub + 2 * FSZ;
    ushort* qb_bf  = ub + 3 * FSZ;
    ushort* wb     = ub + 4 * FSZ;
    ushort* wb1    = wb + 16 * 65536;
    ushort* wb2    = wb1 + 4 * 262144;
    ushort* kvt    = wb2 + 4 * 131072;
    float* kvb = (float*)(kvt + 786432);
    float* ksb = kvb + 524288;
    int* cls0 = (int*)(ksb + 16384);
    int* cls1 = cls0 + 38400;
    int* tl0  = cls1 + 38400;
    int* tl1  = tl0 + 38400;
    int* meta = tl1 + 38400;
    ushort* hid_bf = (ushort*)vbuf;

    lft_wconv_kernel<<<dim3(8, 8, 16), 256, 0, stream>>>(Wq, Wk, Wv, Wm, 256, 256, 4, wb);
    lft_wconv_kernel<<<dim3(16, 16, 4), 256, 0, stream>>>(W1, W1, W1, W1, 512, 512, 1, wb1);
    lft_wconv_kernel<<<dim3(16, 8, 4), 256, 0, stream>>>(W2, W2, W2, W2, 512, 256, 1, wb2);
    lft_cast_kernel<<<19200, 256, 0, stream>>>(feat0, feat1, fa_bf, fb_bf);
    hipMemcpyAsync(out + 20352000L, proto, 2048 * 4, hipMemcpyDeviceToDevice, stream);
    lft_class_kernel<<<300, 256, 0, stream>>>(f0wo, f1wo, mask0, mask1, proto,
                                              out, cls0, cls1);
    lft_sort_kernel<<<16, 256, 0, stream>>>(cls0, cls1, tl0, tl1, meta);

    for (int li = 0; li < 4; li++) {
        const ushort* wq = wb + (size_t)(li * 4 + 0) * 65536;   // [wq|wk|wv|wm] contiguous
        const ushort* wk = wb + (size_t)(li * 4 + 1) * 65536;
        const ushort* wm = wb + (size_t)(li * 4 + 3) * 65536;
        const ushort* w1 = wb1 + (size_t)li * 262144;
        const ushort* w2 = wb2 + (size_t)li * 131072;
        const float* g1p = g1 + li * 256; const float* b1p = b1 + li * 256;
        const float* g2p = g2 + li * 256; const float* b2p = b2 + li * 256;

        auto call = [&](ushort* x_bf, ushort* s_bf, const int* clsx,
                        const int* tlx, const int* mtx,
                        const int* tls, const int* mts,
                        const float* residp, float* outFp, bool selfself) {
            dim3 blk(256);
            if (selfself) {
                // q|k|v fused: one pass over x_bf, N=768 ([wq|wk|wv] contiguous)
                lft_mfma_gemm<<<dim3(6, 300), blk, 0, stream>>>(
                    x_bf, x_bf, 256, wq, kbuf, qb_bf, vbuf, 768, 256, 3);
            } else {
                lft_mfma_gemm<<<dim3(2, 300), blk, 0, stream>>>(
                    x_bf, x_bf, 256, wq, nullptr, qb_bf, nullptr, 256, 256, 1);
                // k|v fused over s_bf, N=512 ([wk|wv] contiguous)
                lft_mfma_gemm<<<dim3(4, 300), blk, 0, stream>>>(
                    s_bf, s_bf, 256, wk, kbuf, nullptr, vbuf, 512, 256, 4);
            }
            hipMemsetAsync(kvb, 0, (524288 + 16384) * 4, stream);
            lft_kv_kernel<<<dim3(KV_NCH, 8, 64), blk, 0, stream>>>(kbuf, vbuf, tls, mts, kvb, ksb);
            lft_kvconv_kernel<<<64, blk, 0, stream>>>(kvb, ksb, kvt);
            lft_msg_kernel<<<dim3(MSG_NCH, 8, 8), blk, 0, stream>>>(qb_bf, kvt, tlx, mtx, msg_bf);
            // msg = LN(msg @ Wm)*g1+b1   (fused GEMM+LN, in-place bf16 out)
            lft_gemm_ln<<<600, blk, 0, stream>>>(msg_bf, msg_bf, 256, wm, 256,
                                                 g1p, b1p, nullptr, nullptr, nullptr, msg_bf);
            // hid = relu([x|msg]@W1)
            lft_mfma_gemm<<<dim3(4, 300), blk, 0, stream>>>(
                x_bf, msg_bf, 256, w1, nullptr, hid_bf, nullptr, 512, 512, 2);
            // out = valid ? resid + LN(hid@W2) : resid   (fused GEMM+LN)
            lft_gemm_ln<<<600, blk, 0, stream>>>(hid_bf, hid_bf, 512, w2, 512,
                                                 g2p, b2p, residp, clsx, outFp, x_bf);
        };

        const float* ra = (li == 0) ? feat0 : fa;
        const float* rb = (li == 0) ? feat1 : fb;
        float* oa = (li == 3) ? out : fa;
        float* ob = (li == 3) ? (out + FSZ) : fb;

        if ((li & 1) == 0) {           // self-self
            call(fa_bf, fa_bf, cls0, tl0, meta,       tl0, meta,       ra, oa, true);
            call(fb_bf, fb_bf, cls1, tl1, meta + 128, tl1, meta + 128, rb, ob, true);
        } else {                       // cross-self
            call(fa_bf, fb_bf, cls0, tl0, meta,       tl1, meta + 128, ra, oa, false);
            call(fb_bf, fa_bf, cls1, tl1, meta + 128, tl0, meta,       rb, ob, false);
        }
    }
}

// Round 2
// 2169.183 us; speedup vs baseline: 1.0313x; 1.0313x over previous
//
#include <hip/hip_runtime.h>
#include <math.h>

#define NPROTO 8
#define KV_NCH 4
#define MSG_NCH 8

typedef __attribute__((ext_vector_type(8))) short short8;
typedef __attribute__((ext_vector_type(4))) float floatx4;

static __device__ __forceinline__ ushort f2b(float f) {
    unsigned u = __builtin_bit_cast(unsigned, f);
    unsigned r = (u + 0x7fffu + ((u >> 16) & 1u)) >> 16;
    return (ushort)r;
}

static __device__ __forceinline__ float elu1(float v) {
    return v > 0.f ? v + 1.f : __expf(v);
}

// async 16B global -> LDS (linear dest: wave base + lane*16B)
#define GLOAD16(gp, lp) __builtin_amdgcn_global_load_lds( \
    (const __attribute__((address_space(1))) void*)(gp),  \
    (__attribute__((address_space(3))) void*)(lp), 16, 0, 0)

// drain staging loads + retire LDS reads, then raw barrier (memory-fenced)
#define WAIT_BAR() asm volatile("s_waitcnt vmcnt(0) lgkmcnt(0)\n\ts_barrier" ::: "memory")

// swizzle of the 16B-group index within a 32-col bf16 row (4 groups/row):
// lds[r][cg] holds global[r][cg ^ g(r)], g(r) = (r>>1)&3 -> 2-way (free) banks
static __device__ __forceinline__ int swz(int r) { return (r >> 1) & 3; }

// ---------------- prototype projection / argmax-class kernel ----------------
__global__ __launch_bounds__(256) void lft_class_kernel(
    const float* __restrict__ f0wo, const float* __restrict__ f1wo,
    const int* __restrict__ mask0, const int* __restrict__ mask1,
    const float* __restrict__ proto,
    float* out, int* cls0, int* cls1)
{
    __shared__ float pr[2048];          // proto [8][256]
    __shared__ float tile[256][64];     // [token][ch], swizzled in ch
    int t = threadIdx.x;
    *(float4*)&pr[t * 4]        = *(const float4*)&proto[t * 4];
    *(float4*)&pr[1024 + t * 4] = *(const float4*)&proto[1024 + t * 4];
    long tok0 = (long)blockIdx.x * 256;
    const float* fsrc; const int* msrc; float* fpout; float* clsout; int* clsarr; long tbase;
    if (tok0 < 38400) {
        tbase = tok0; fsrc = f0wo; msrc = mask0;
        fpout = out + 19737600L; clsout = out + 19660800L; clsarr = cls0;
    } else {
        tbase = tok0 - 38400; fsrc = f1wo; msrc = mask1;
        fpout = out + 20044800L; clsout = out + 19699200L; clsarr = cls1;
    }
    float s[NPROTO] = {};
    int r0 = t >> 4;            // 0..15
    int c4 = (t & 15) << 2;     // 0..60
    for (int ct = 0; ct < 4; ct++) {
        __syncthreads();
#pragma unroll
        for (int rr = 0; rr < 16; rr++) {
            int row = rr * 16 + r0;
            float4 v = *(const float4*)&fsrc[(tbase + row) * 256 + ct * 64 + c4];
            *(float4*)&tile[row][c4 ^ ((row & 7) << 2)] = v;
        }
        __syncthreads();
#pragma unroll
        for (int cc = 0; cc < 16; cc++) {
            float4 f = *(const float4*)&tile[t][(cc << 2) ^ ((t & 7) << 2)];
#pragma unroll
            for (int p = 0; p < NPROTO; p++) {
                float4 pv = *(const float4*)&pr[p * 256 + ct * 64 + (cc << 2)];
                s[p] += f.x * pv.x + f.y * pv.y + f.z * pv.z + f.w * pv.w;
            }
        }
    }
    long tok = tbase + t;
    int best = 0; float bv = s[0];
#pragma unroll
    for (int p = 1; p < NPROTO; p++) { if (s[p] > bv) { bv = s[p]; best = p; } }
#pragma unroll
    for (int p = 0; p < NPROTO; p++) fpout[tok * 8 + p] = s[p];
    clsout[tok] = (float)best;
    clsarr[tok] = msrc[tok] ? best : -1;
}

// ---------------- counting sort of tokens by (batch,class) -------------------
__global__ __launch_bounds__(256) void lft_sort_kernel(
    const int* __restrict__ cls0, const int* __restrict__ cls1,
    int* tl0, int* tl1, int* meta)
{
    int g = blockIdx.x; int L = g >> 3, b = g & 7;
    const int* cls = (L ? cls1 : cls0) + b * 4800;
    int* tl = (L ? tl1 : tl0) + b * 4800;
    int* mt = meta + (L * 8 + b) * 16;
    __shared__ int cnt[8], base[8], pos[8];
    int t = threadIdx.x;
    if (t < 8) cnt[t] = 0;
    __syncthreads();
    for (int tok = t; tok < 4800; tok += 256) {
        int c = cls[tok];
        if (c >= 0) atomicAdd(&cnt[c], 1);
    }
    __syncthreads();
    if (t == 0) {
        int s = 0;
        for (int c = 0; c < 8; c++) { base[c] = s; pos[c] = s; s += cnt[c]; }
    }
    __syncthreads();
    if (t < 8) { mt[t * 2] = base[t]; mt[t * 2 + 1] = cnt[t]; }
    for (int tok = t; tok < 4800; tok += 256) {
        int c = cls[tok];
        if (c >= 0) { int p = atomicAdd(&pos[c], 1); tl[p] = tok; }
    }
}

// ---------------- weight convert + transpose: Wt[n*K+k] = bf16(W[k*N+n]) ----
__global__ __launch_bounds__(256) void lft_wconv_kernel(
    const float* W0, const float* W1p, const float* W2p, const float* W3p,
    int K, int N, int nTypes, ushort* dst)
{
    int z = blockIdx.z;
    int li = z / nTypes, mi = z % nTypes;
    const float* srcs[4] = {W0, W1p, W2p, W3p};
    const float* src = srcs[mi] + (size_t)li * K * N;
    ushort* outp = dst + (size_t)z * K * N;
    __shared__ float tile[32][33];
    int k0 = blockIdx.x * 32, n0 = blockIdx.y * 32;
    int t = threadIdx.x;
    int r = t >> 3, c4 = (t & 7) << 2;
    float4 v = *(const float4*)&src[(size_t)(k0 + r) * N + n0 + c4];
    tile[r][c4] = v.x; tile[r][c4 + 1] = v.y; tile[r][c4 + 2] = v.z; tile[r][c4 + 3] = v.w;
    __syncthreads();
    ushort4 o;
    o.x = f2b(tile[c4 + 0][r]);
    o.y = f2b(tile[c4 + 1][r]);
    o.z = f2b(tile[c4 + 2][r]);
    o.w = f2b(tile[c4 + 3][r]);
    *(ushort4*)&outp[(size_t)(n0 + r) * K + k0 + c4] = o;
}

// ---------------- bf16 cast of feat0/feat1 (shadows only) ----------------
__global__ __launch_bounds__(256) void lft_cast_kernel(
    const float* __restrict__ f0, const float* __restrict__ f1,
    ushort* fab, ushort* fbb)
{
    long idx = ((long)blockIdx.x * 256 + threadIdx.x) * 4;
    const float* src; ushort* db; long o;
    if (idx < 9830400L) { src = f0; db = fab; o = idx; }
    else                { src = f1; db = fbb; o = idx - 9830400L; }
    float4 v = *(const float4*)&src[o];
    ushort4 u; u.x = f2b(v.x); u.y = f2b(v.y); u.z = f2b(v.z); u.w = f2b(v.w);
    *(ushort4*)&db[o] = u;
}

// ---------------- bf16 MFMA GEMM: C[38400,N] = act([A0|A1] @ Wt^T) ----------
// Counted 2-phase pipeline: global_load_lds (16B) into linear swizzled LDS,
// double-buffered; one vmcnt/lgkm drain + raw barrier per K-step.
// act: 0 none, 1 elu+1, 2 relu  -> Cf (fp32, stride N) / Cb (bf16, stride N)
// act 3: qkv-fused N=768: col<256 -> Cb=q bf16 elu ; <512 -> Cf=phi_k fp32 ;
//        else Cv=v fp32.   act 4: kv-fused N=512: Cf=phi_k ; Cv=v.
__global__ __launch_bounds__(256) void lft_mfma_gemm(
    const ushort* __restrict__ A0, const ushort* __restrict__ A1, int kSplit,
    const ushort* __restrict__ Wt,
    float* Cf, ushort* Cb, float* Cv, int N, int K, int act)
{
    __shared__ ushort As[2][128 * 32];
    __shared__ ushort Bs[2][128 * 32];
    int t = threadIdx.x;
    int m0 = blockIdx.y << 7;
    int n0 = blockIdx.x << 7;
    int wv = t >> 6, lane = t & 63;
    int wm = wv >> 1, wn = wv & 1;
    int l16 = lane & 15, quad = lane >> 4;
    floatx4 acc[4][4] = {};

    int lrow = lane >> 2;          // 0..15 row-within-group
    int lcg = lane & 3;            // 16B group 0..3

    auto stage = [&](int buf, int k0) {
        const ushort* Asrc; int kcol, ldA;
        if (k0 < kSplit) { Asrc = A0; kcol = k0;          ldA = kSplit; }
        else             { Asrc = A1; kcol = k0 - kSplit; ldA = K - kSplit; }
        ushort* Ab = &As[buf][0];
        ushort* Bb = &Bs[buf][0];
#pragma unroll
        for (int s = 0; s < 2; s++) {
            int r = s * 64 + wv * 16 + lrow;
            int cgA = (lcg ^ swz(r)) << 3;
            GLOAD16(&Asrc[(size_t)(m0 + r) * ldA + kcol + cgA], &Ab[(s * 64 + wv * 16) * 32]);
            GLOAD16(&Wt[(size_t)(n0 + r) * K + k0 + cgA], &Bb[(s * 64 + wv * 16) * 32]);
        }
    };

    int nt = K >> 5;
    stage(0, 0);
    WAIT_BAR();
    int cur = 0;
    for (int tt = 0; tt < nt; ++tt) {
        if (tt + 1 < nt) stage(cur ^ 1, (tt + 1) << 5);
        const ushort* Ab = &As[cur][0];
        const ushort* Bb = &Bs[cur][0];
        short8 af[4], bfr[4];
#pragma unroll
        for (int i = 0; i < 4; i++) {
            int rA = wm * 64 + i * 16 + l16;
            int rB = wn * 64 + i * 16 + l16;
            af[i]  = *(const short8*)&Ab[rA * 32 + ((quad ^ swz(rA)) << 3)];
            bfr[i] = *(const short8*)&Bb[rB * 32 + ((quad ^ swz(rB)) << 3)];
        }
#pragma unroll
        for (int i = 0; i < 4; i++)
#pragma unroll
            for (int j = 0; j < 4; j++)
                acc[i][j] = __builtin_amdgcn_mfma_f32_16x16x32_bf16(af[i], bfr[j], acc[i][j], 0, 0, 0);
        if (tt + 1 < nt) { WAIT_BAR(); cur ^= 1; }
    }
#pragma unroll
    for (int i = 0; i < 4; i++) {
#pragma unroll
        for (int j = 0; j < 4; j++) {
#pragma unroll
            for (int r = 0; r < 4; r++) {
                float v = acc[i][j][r];
                long row = m0 + wm * 64 + i * 16 + quad * 4 + r;
                int col = n0 + wn * 64 + j * 16 + l16;
                if (act == 3) {
                    if (col < 256)      Cb[row * 256 + col] = f2b(elu1(v));
                    else if (col < 512) Cf[row * 256 + col - 256] = elu1(v);
                    else                Cv[row * 256 + col - 512] = v;
                } else if (act == 4) {
                    if (col < 256) Cf[row * 256 + col] = elu1(v);
                    else           Cv[row * 256 + col - 256] = v;
                } else {
                    if (act == 1)      v = elu1(v);
                    else if (act == 2) v = fmaxf(v, 0.f);
                    if (Cf) Cf[row * N + col] = v;
                    if (Cb) Cb[row * N + col] = f2b(v);
                }
            }
        }
    }
}

// ---------------- fused GEMM (N=256) + row-LayerNorm epilogue ----------------
// Same counted 2-phase pipeline. Tile: M=64 rows/block (grid 600), all 256
// cols; wave w owns cols [64w,64w+64).
__global__ __launch_bounds__(256) void lft_gemm_ln(
    const ushort* __restrict__ A0, const ushort* __restrict__ A1, int kSplit,
    const ushort* __restrict__ Wt, int K,
    const float* __restrict__ g, const float* __restrict__ bb,
    const float* __restrict__ resid, const int* __restrict__ cls,
    float* outF, ushort* __restrict__ outB)
{
    __shared__ ushort As[2][64 * 32];
    __shared__ ushort Bs[2][256 * 32];
    __shared__ float gs[256], bs[256];
    __shared__ float psum[4][64], psq[4][64];
    int t = threadIdx.x;
    long m0 = (long)blockIdx.x << 6;
    int wv = t >> 6, lane = t & 63;
    int l16 = lane & 15, quad = lane >> 4;
    gs[t] = g[t]; bs[t] = bb[t];
    floatx4 acc[4][4] = {};

    int lrow = lane >> 2;
    int lcg = lane & 3;

    auto stage = [&](int buf, int k0) {
        const ushort* Asrc; int kcol, ldA;
        if (k0 < kSplit) { Asrc = A0; kcol = k0;          ldA = kSplit; }
        else             { Asrc = A1; kcol = k0 - kSplit; ldA = K - kSplit; }
        ushort* Ab = &As[buf][0];
        ushort* Bb = &Bs[buf][0];
        {
            int r = wv * 16 + lrow;
            int cgA = (lcg ^ swz(r)) << 3;
            GLOAD16(&Asrc[(m0 + r) * ldA + kcol + cgA], &Ab[(wv * 16) * 32]);
        }
#pragma unroll
        for (int s = 0; s < 4; s++) {
            int r = s * 64 + wv * 16 + lrow;
            int cgB = (lcg ^ swz(r)) << 3;
            GLOAD16(&Wt[(size_t)r * K + k0 + cgB], &Bb[(s * 64 + wv * 16) * 32]);
        }
    };

    int nt = K >> 5;
    stage(0, 0);
    WAIT_BAR();
    int cur = 0;
    for (int tt = 0; tt < nt; ++tt) {
        if (tt + 1 < nt) stage(cur ^ 1, (tt + 1) << 5);
        const ushort* Ab = &As[cur][0];
        const ushort* Bb = &Bs[cur][0];
        short8 af[4], bfr[4];
#pragma unroll
        for (int i = 0; i < 4; i++) {
            int rA = i * 16 + l16;
            int rB = wv * 64 + i * 16 + l16;
            af[i]  = *(const short8*)&Ab[rA * 32 + ((quad ^ swz(rA)) << 3)];
            bfr[i] = *(const short8*)&Bb[rB * 32 + ((quad ^ swz(rB)) << 3)];
        }
#pragma unroll
        for (int i = 0; i < 4; i++)
#pragma unroll
            for (int j = 0; j < 4; j++)
                acc[i][j] = __builtin_amdgcn_mfma_f32_16x16x32_bf16(af[i], bfr[j], acc[i][j], 0, 0, 0);
        if (tt + 1 < nt) { WAIT_BAR(); cur ^= 1; }
    }
    // per-row partial sums (this wave's 64 cols) -> LDS
#pragma unroll
    for (int i = 0; i < 4; i++) {
#pragma unroll
        for (int r = 0; r < 4; r++) {
            float s = 0.f, q = 0.f;
#pragma unroll
            for (int j = 0; j < 4; j++) { float v = acc[i][j][r]; s += v; q += v * v; }
#pragma unroll
            for (int o = 8; o >= 1; o >>= 1) {
                s += __shfl_xor(s, o, 64);
                q += __shfl_xor(q, o, 64);
            }
            if (l16 == 0) {
                int row = i * 16 + quad * 4 + r;
                psum[wv][row] = s; psq[wv][row] = q;
            }
        }
    }
    __syncthreads();
    if (t < 64) {
        float s = psum[0][t] + psum[1][t] + psum[2][t] + psum[3][t];
        float q = psq[0][t] + psq[1][t] + psq[2][t] + psq[3][t];
        float mean = s * (1.0f / 256.0f);
        float var = q * (1.0f / 256.0f) - mean * mean;
        psum[0][t] = mean;
        psq[0][t] = rsqrtf(var + 1e-5f);
    }
    __syncthreads();
#pragma unroll
    for (int i = 0; i < 4; i++) {
#pragma unroll
        for (int r = 0; r < 4; r++) {
            int rloc = i * 16 + quad * 4 + r;
            long grow = m0 + rloc;
            float mean = psum[0][rloc], rstd = psq[0][rloc];
            int cv = cls ? cls[grow] : 0;
#pragma unroll
            for (int j = 0; j < 4; j++) {
                int col = wv * 64 + j * 16 + l16;
                float y = (acc[i][j][r] - mean) * rstd * gs[col] + bs[col];
                if (resid) {
                    float xr = resid[grow * 256 + col];
                    y = (cv >= 0) ? xr + y : xr;
                }
                if (outF) outF[grow * 256 + col] = y;
                outB[grow * 256 + col] = f2b(y);
            }
        }
    }
}

// ---------------- per-class KV / Ksum reduction (SRC-side token lists) --------
__global__ __launch_bounds__(256) void lft_kv_kernel(
    const float* __restrict__ phik, const float* __restrict__ vmat,
    const int* __restrict__ tlist, const int* __restrict__ meta,
    float* kv, float* ksum)
{
    int chunk = blockIdx.x, c = blockIdx.y;
    int b = blockIdx.z >> 3, h = blockIdx.z & 7;
    int off = meta[(b * 8 + c) * 2], n = meta[(b * 8 + c) * 2 + 1];
    int per = (n + KV_NCH - 1) / KV_NCH;
    int s0 = chunk * per;
    int s1 = min(s0 + per, n);
    if (s0 >= s1) return;
    const int* tl = tlist + b * 4800 + off;
    int t = threadIdx.x;
    __shared__ float kb[8][32];
    __shared__ float vb[8][32];
    int od = t >> 3, oe = (t & 7) << 2;
    int lt = t >> 5, ld = t & 31;
    float a0 = 0.f, a1 = 0.f, a2 = 0.f, a3 = 0.f, ak = 0.f;
    for (int s = s0; s < s1; s += 8) {
        float kval = 0.f, vval = 0.f;
        if (s + lt < s1) {
            int tok = tl[s + lt];
            long bse = ((long)b * 4800 + tok) * 256 + h * 32 + ld;
            kval = phik[bse];
            vval = vmat[bse];
        }
        __syncthreads();
        kb[lt][ld] = kval;
        vb[lt][ld] = vval;
        __syncthreads();
#pragma unroll
        for (int j = 0; j < 8; j++) {
            float kd = kb[j][od];
            float4 vv = *(const float4*)&vb[j][oe];
            a0 += kd * vv.x; a1 += kd * vv.y; a2 += kd * vv.z; a3 += kd * vv.w;
            ak += kd;
        }
    }
    float* dst = kv + (((long)(b * NPROTO + c) * 8 + h) << 10) + od * 32 + oe;
    atomicAdd(dst + 0, a0);
    atomicAdd(dst + 1, a1);
    atomicAdd(dst + 2, a2);
    atomicAdd(dst + 3, a3);
    if ((t & 7) == 0)
        atomicAdd(ksum + (((long)(b * NPROTO + c) * 8 + h) << 5) + od, ak);
}

// ---------------- kv fp32 [d][e] + ksum → bf16 B-layout [e'][d], e'<48 -------
__global__ __launch_bounds__(256) void lft_kvconv_kernel(
    const float* __restrict__ kvb, const float* __restrict__ ksb,
    ushort* __restrict__ kvt)
{
    int bc = blockIdx.x;          // b*8+c
    int t = threadIdx.x;
    int h = t >> 5, d = t & 31;
    const float* kvsrc = kvb + ((long)bc * 8 + h) * 1024;
    const float* kssrc = ksb + ((long)bc * 8 + h) * 32;
    ushort* dst = kvt + ((long)bc * 8 + h) * 1536;
#pragma unroll
    for (int e = 0; e < 32; e++) dst[e * 32 + d] = f2b(kvsrc[d * 32 + e]);
    dst[32 * 32 + d] = f2b(kssrc[d]);
#pragma unroll
    for (int e = 33; e < 48; e++) dst[e * 32 + d] = 0;
}

// ---------------- msg via MFMA over X-SIDE class-sorted lists ----------------
__global__ __launch_bounds__(256) void lft_msg_kernel(
    const ushort* __restrict__ pq, const ushort* __restrict__ kvt,
    const int* __restrict__ tlist, const int* __restrict__ meta,
    ushort* __restrict__ msg)
{
    int chunk = blockIdx.x, c = blockIdx.y, b = blockIdx.z;
    int off = meta[(b * 8 + c) * 2], n = meta[(b * 8 + c) * 2 + 1];
    int per = (n + MSG_NCH - 1) / MSG_NCH;
    int s0 = chunk * per, s1 = min(s0 + per, n);
    if (s0 >= s1) return;
    const int* tl = tlist + b * 4800 + off;
    int t = threadIdx.x;
    int wave = t >> 6, lane = t & 63;
    int l16 = lane & 15, quad = lane >> 4;
    int bc = b * 8 + c;
    short8 bfr[2][3];
#pragma unroll
    for (int hh = 0; hh < 2; hh++) {
        int h = wave * 2 + hh;
        const ushort* kb = kvt + ((long)bc * 8 + h) * 1536;
#pragma unroll
        for (int nt = 0; nt < 3; nt++)
            bfr[hh][nt] = *(const short8*)&kb[(nt * 16 + l16) * 32 + quad * 8];
    }
    for (int s = s0; s < s1; s += 16) {
        int ia = min(s + l16, s1 - 1);
        int tokA = tl[ia];
        long rowA = (long)b * 4800 + tokA;
#pragma unroll
        for (int hh = 0; hh < 2; hh++) {
            int h = wave * 2 + hh;
            short8 a = *(const short8*)&pq[rowA * 256 + h * 32 + quad * 8];
            floatx4 n0 = {}, n1 = {}, dd = {};
            n0 = __builtin_amdgcn_mfma_f32_16x16x32_bf16(a, bfr[hh][0], n0, 0, 0, 0);
            n1 = __builtin_amdgcn_mfma_f32_16x16x32_bf16(a, bfr[hh][1], n1, 0, 0, 0);
            dd = __builtin_amdgcn_mfma_f32_16x16x32_bf16(a, bfr[hh][2], dd, 0, 0, 0);
#pragma unroll
            for (int r = 0; r < 4; r++) {
                int rowi = s + quad * 4 + r;
                float den = __shfl(dd[r], lane & 48, 64);
                float inv = 1.f / (den + 1e-6f);
                int tokr = __shfl(tokA, quad * 4 + r, 64);
                if (rowi < s1) {
                    long base = ((long)b * 4800 + tokr) * 256 + h * 32;
                    msg[base + l16]      = f2b(n0[r] * inv);
                    msg[base + 16 + l16] = f2b(n1[r] * inv);
                }
            }
        }
    }
}

extern "C" void kernel_launch(void* const* d_in, const int* in_sizes, int n_in,
                              void* d_out, int out_size, void* d_ws, size_t ws_size,
                              hipStream_t stream)
{
    (void)in_sizes; (void)n_in; (void)out_size; (void)ws_size;
    const float* feat0 = (const float*)d_in[0];
    const float* feat1 = (const float*)d_in[1];
    const int*   mask0 = (const int*)d_in[2];
    const int*   mask1 = (const int*)d_in[3];
    const float* f0wo  = (const float*)d_in[4];
    const float* f1wo  = (const float*)d_in[5];
    const float* proto = (const float*)d_in[6];
    const float* Wq = (const float*)d_in[7];
    const float* Wk = (const float*)d_in[8];
    const float* Wv = (const float*)d_in[9];
    const float* Wm = (const float*)d_in[10];
    const float* W1 = (const float*)d_in[11];
    const float* W2 = (const float*)d_in[12];
    const float* g1 = (const float*)d_in[13];
    const float* b1 = (const float*)d_in[14];
    const float* g2 = (const float*)d_in[15];
    const float* b2 = (const float*)d_in[16];
    float* out = (float*)d_out;
    float* ws = (float*)d_ws;

    // ---- workspace layout (unchanged) ----
    const long FSZ = 9830400L;           // 8*4800*256
    float* fa   = ws;
    float* fb   = ws + FSZ;
    float* kbuf = ws + 2 * FSZ;          // phi_k fp32
    float* vbuf = ws + 3 * FSZ;          // v fp32 ; later reused as hid_bf
    ushort* ub  = (ushort*)(ws + 4 * FSZ);
    ushort* fa_bf  = ub;
    ushort* fb_bf  = ub + FSZ;
    ushort* msg_bf = ub + 2 * FSZ;
    ushort* qb_bf  = ub + 3 * FSZ;
    ushort* wb     = ub + 4 * FSZ;
    ushort* wb1    = wb + 16 * 65536;
    ushort* wb2    = wb1 + 4 * 262144;
    ushort* kvt    = wb2 + 4 * 131072;
    float* kvb = (float*)(kvt + 786432);
    float* ksb = kvb + 524288;
    int* cls0 = (int*)(ksb + 16384);
    int* cls1 = cls0 + 38400;
    int* tl0  = cls1 + 38400;
    int* tl1  = tl0 + 38400;
    int* meta = tl1 + 38400;
    ushort* hid_bf = (ushort*)vbuf;

    lft_wconv_kernel<<<dim3(8, 8, 16), 256, 0, stream>>>(Wq, Wk, Wv, Wm, 256, 256, 4, wb);
    lft_wconv_kernel<<<dim3(16, 16, 4), 256, 0, stream>>>(W1, W1, W1, W1, 512, 512, 1, wb1);
    lft_wconv_kernel<<<dim3(16, 8, 4), 256, 0, stream>>>(W2, W2, W2, W2, 512, 256, 1, wb2);
    lft_cast_kernel<<<19200, 256, 0, stream>>>(feat0, feat1, fa_bf, fb_bf);
    hipMemcpyAsync(out + 20352000L, proto, 2048 * 4, hipMemcpyDeviceToDevice, stream);
    lft_class_kernel<<<300, 256, 0, stream>>>(f0wo, f1wo, mask0, mask1, proto,
                                              out, cls0, cls1);
    lft_sort_kernel<<<16, 256, 0, stream>>>(cls0, cls1, tl0, tl1, meta);

    for (int li = 0; li < 4; li++) {
        const ushort* wq = wb + (size_t)(li * 4 + 0) * 65536;   // [wq|wk|wv|wm] contiguous
        const ushort* wk = wb + (size_t)(li * 4 + 1) * 65536;
        const ushort* wm = wb + (size_t)(li * 4 + 3) * 65536;
        const ushort* w1 = wb1 + (size_t)li * 262144;
        const ushort* w2 = wb2 + (size_t)li * 131072;
        const float* g1p = g1 + li * 256; const float* b1p = b1 + li * 256;
        const float* g2p = g2 + li * 256; const float* b2p = b2 + li * 256;

        auto call = [&](ushort* x_bf, ushort* s_bf, const int* clsx,
                        const int* tlx, const int* mtx,
                        const int* tls, const int* mts,
                        const float* residp, float* outFp, bool selfself) {
            dim3 blk(256);
            if (selfself) {
                // q|k|v fused: one pass over x_bf, N=768 ([wq|wk|wv] contiguous)
                lft_mfma_gemm<<<dim3(6, 300), blk, 0, stream>>>(
                    x_bf, x_bf, 256, wq, kbuf, qb_bf, vbuf, 768, 256, 3);
            } else {
                lft_mfma_gemm<<<dim3(2, 300), blk, 0, stream>>>(
                    x_bf, x_bf, 256, wq, nullptr, qb_bf, nullptr, 256, 256, 1);
                // k|v fused over s_bf, N=512 ([wk|wv] contiguous)
                lft_mfma_gemm<<<dim3(4, 300), blk, 0, stream>>>(
                    s_bf, s_bf, 256, wk, kbuf, nullptr, vbuf, 512, 256, 4);
            }
            hipMemsetAsync(kvb, 0, (524288 + 16384) * 4, stream);
            lft_kv_kernel<<<dim3(KV_NCH, 8, 64), blk, 0, stream>>>(kbuf, vbuf, tls, mts, kvb, ksb);
            lft_kvconv_kernel<<<64, blk, 0, stream>>>(kvb, ksb, kvt);
            lft_msg_kernel<<<dim3(MSG_NCH, 8, 8), blk, 0, stream>>>(qb_bf, kvt, tlx, mtx, msg_bf);
            // msg = LN(msg @ Wm)*g1+b1   (fused GEMM+LN, in-place bf16 out)
            lft_gemm_ln<<<600, blk, 0, stream>>>(msg_bf, msg_bf, 256, wm, 256,
                                                 g1p, b1p, nullptr, nullptr, nullptr, msg_bf);
            // hid = relu([x|msg]@W1)
            lft_mfma_gemm<<<dim3(4, 300), blk, 0, stream>>>(
                x_bf, msg_bf, 256, w1, nullptr, hid_bf, nullptr, 512, 512, 2);
            // out = valid ? resid + LN(hid@W2) : resid   (fused GEMM+LN)
            lft_gemm_ln<<<600, blk, 0, stream>>>(hid_bf, hid_bf, 512, w2, 512,
                                                 g2p, b2p, residp, clsx, outFp, x_bf);
        };

        const float* ra = (li == 0) ? feat0 : fa;
        const float* rb = (li == 0) ? feat1 : fb;
        float* oa = (li == 3) ? out : fa;
        float* ob = (li == 3) ? (out + FSZ) : fb;

        if ((li & 1) == 0) {           // self-self
            call(fa_bf, fa_bf, cls0, tl0, meta,       tl0, meta,       ra, oa, true);
            call(fb_bf, fb_bf, cls1, tl1, meta + 128, tl1, meta + 128, rb, ob, true);
        } else {                       // cross-self
            call(fa_bf, fb_bf, cls0, tl0, meta,       tl1, meta + 128, ra, oa, false);
            call(fb_bf, fa_bf, cls1, tl1, meta + 128, tl0, meta,       rb, ob, false);
        }
    }
}